// Round 22
// baseline (58.525 us; speedup 1.0000x reference)
//
#include <hip/hip_runtime.h>
#include <stdint.h>

#define OUTD 4000
#define NPAD 4096
#define CC 16
#define WW 48
#define HH 48
#define BB 128
#define KD 768          // C*H contraction depth
#define MD 6144         // B*W rows
#define EPSF 1e-6f

#define BM 192          // 4 batches * 48 w
#define BNB 256
#define BKU 32          // K elems per unit
#define UNITS 24        // 768/32
#define AELEMS (BM * BKU)              // 6144 elems = 12 chunks
#define SLOT_ELEMS ((BM + BNB) * BKU)  // 14336 elems = 28 KB
#define THREADS 256
#define XPB 1152        // blocks for x-conversion (16 elems/thread)

using short8  = __attribute__((ext_vector_type(8))) short;
using short16 = __attribute__((ext_vector_type(16))) short;
using f32x4   = __attribute__((ext_vector_type(4))) float;

static __device__ __forceinline__ unsigned short f2bf(float f) {
  union { float f; unsigned int u; } v; v.f = f;
  unsigned int u = v.u;
  unsigned int r = (u + 0x7FFFu + ((u >> 16) & 1u)) >> 16;
  return (unsigned short)r;
}

// ---------------- Fused prep: blocks [0,XPB) convert x -> A (bf16, merged (c,h) K axis,
// 16 elems/thread); blocks [XPB, XPB+1024) normalize weights -> Qt (bf16) + wnT (f32).
__global__ __launch_bounds__(256)
void prep_all(const float* __restrict__ x,
              const float* __restrict__ width,
              const float* __restrict__ height,
              const float* __restrict__ feat,
              unsigned short* __restrict__ A,
              unsigned short* __restrict__ Qt,
              float* __restrict__ wnT) {
  __shared__ float smw[4][WW];
  int bid = blockIdx.x;
  if (bid < XPB) {
    int t = bid * 256 + threadIdx.x;      // XPB*256*16 == BB*CC*WW*HH exactly
    int e = t * 16;
    int h0 = e % HH;                      // 16 | 48: the 16 elems share (b,c,w)
    int w = (e / HH) % WW;
    int c = (e / (HH * WW)) % CC;
    int b = e / (HH * WW * CC);
    float4 v0 = *(const float4*)(x + e);
    float4 v1 = *(const float4*)(x + e + 4);
    float4 v2 = *(const float4*)(x + e + 8);
    float4 v3 = *(const float4*)(x + e + 12);
    short16 o;
    o[0]  = (short)f2bf(v0.x); o[1]  = (short)f2bf(v0.y);
    o[2]  = (short)f2bf(v0.z); o[3]  = (short)f2bf(v0.w);
    o[4]  = (short)f2bf(v1.x); o[5]  = (short)f2bf(v1.y);
    o[6]  = (short)f2bf(v1.z); o[7]  = (short)f2bf(v1.w);
    o[8]  = (short)f2bf(v2.x); o[9]  = (short)f2bf(v2.y);
    o[10] = (short)f2bf(v2.z); o[11] = (short)f2bf(v2.w);
    o[12] = (short)f2bf(v3.x); o[13] = (short)f2bf(v3.y);
    o[14] = (short)f2bf(v3.z); o[15] = (short)f2bf(v3.w);
    *(short16*)&A[(size_t)(b * WW + w) * KD + c * HH + h0] = o;
  } else {
    int lane = threadIdx.x & 63;
    int wv = threadIdx.x >> 6;            // wave 0..3
    int nbase = (bid - XPB) * 4;
    int n = nbase + wv;                   // 0..4095
    bool valid = (n < OUTD);
    float hv = (valid && lane < HH) ? height[n * HH + lane] : 0.f;
    float wvv = (valid && lane < WW) ? width[n * WW + lane] : 0.f;
    float hs = hv * hv, wsum = wvv * wvv;
    #pragma unroll
    for (int off = 32; off > 0; off >>= 1) {
      hs += __shfl_xor(hs, off);
      wsum += __shfl_xor(wsum, off);
    }
    float hnorm = rsqrtf(hs + EPSF);
    float wnorm = rsqrtf(wsum + EPSF);
    if (lane < WW) smw[wv][lane] = wvv * wnorm;   // 0 for invalid n
    if (valid) {
      #pragma unroll
      for (int i = lane; i < KD; i += 64) {
        int c = i / HH, h = i % HH;
        Qt[(size_t)n * KD + i] = f2bf(feat[n * CC + c] * height[n * HH + h] * hnorm);
      }
    } else {
      #pragma unroll
      for (int i = lane; i < KD; i += 64) Qt[(size_t)n * KD + i] = 0;
    }
    __syncthreads();
    if (threadIdx.x < WW) {
      int w = threadIdx.x;
      float4 o = make_float4(smw[0][w], smw[1][w], smw[2][w], smw[3][w]);
      *(float4*)&wnT[w * NPAD + nbase] = o;
    }
  }
}

// ---------------- Main GEMM: P = A (6144x768) * Qt^T (768x4096), fused w-reduction epilogue.
// r15 geometry, UNSPILLED: 192x256 block, FOUR waves of 96x128 (acc 192 AGPR).
// __launch_bounds__(256, 1): min 1 wave/EU -> 512-reg budget per wave (the never-tested
// combination; r15's (256,2) requested the 256 cap and spilled). LDS-read bytes/FLOP is
// 30% lower than the r12 plateau kernel. Occupancy 1 wave/SIMD by construction.
// Ring-2 x 28KB slots, one barrier/unit, counted vmcnt(7) with 1-unit DMA lead.
__global__ __launch_bounds__(THREADS, 1)
void gemm_main(const unsigned short* __restrict__ A,   // [6144][768] bf16 bits
               const unsigned short* __restrict__ Qt,  // [4096][768] bf16 bits
               const float* __restrict__ wnT,          // [48][4096]
               const float* __restrict__ bias,         // [4000]
               float* __restrict__ out) {              // [128][4000]
  __shared__ unsigned short S[2 * SLOT_ELEMS];   // 57344 B

  int tid = threadIdx.x;
  int lane = tid & 63;
  int wid = tid >> 6;          // 0..3
  int wm = wid >> 1;           // 0..1 -> 96-row slice
  int wn = wid & 1;            // 0..1 -> 128-col half

  // 512 blocks: XCD k (= bid&7) owns by in [4k, 4k+4) (A-share 1.15MB, L2-resident),
  // sweeps 16 bx-groups.
  int bid = blockIdx.x;        // 0..511
  int xcd = bid & 7;
  int i = bid >> 3;            // 0..63
  int by = xcd * 4 + (i & 3);  // 0..31
  int bxg = i >> 2;            // 0..15
  int n0 = bxg * BNB;
  int m0 = by * BM;

  // ---- staging: per wave 3 A-chunks + 4 B-chunks per unit (chunk: 16 rows x 32 elems = 1KB).
  // LDS dest linear; global source granule XOR-pre-swizzled (granule 16B, row 64B):
  // LDS[row][g*8..] holds global[row][(g ^ ((row>>1)&3))*8..].
  int lrow = lane >> 2;              // 0..15 row within chunk
  int g = lane & 3;                  // granule
  int gsw = (g ^ ((lrow >> 1) & 3)) * 8;
  const unsigned short* gsrc[7];
  int ldst[7];
  #pragma unroll
  for (int j = 0; j < 3; ++j) {      // A chunks: wid*3+j (0..11)
    int c = wid * 3 + j;
    gsrc[j] = A + (size_t)(m0 + c * 16 + lrow) * KD + gsw;
    ldst[j] = c * 512;
  }
  #pragma unroll
  for (int j = 0; j < 4; ++j) {      // B chunks: wid*4+j (0..15)
    int c = wid * 4 + j;
    gsrc[3 + j] = Qt + (size_t)(n0 + c * 16 + lrow) * KD + gsw;
    ldst[3 + j] = AELEMS + c * 512;
  }

#define SLOTB(u) (((u) & 1) * SLOT_ELEMS)
#define STAGE(u)                                                                  \
  { _Pragma("unroll")                                                             \
    for (int j = 0; j < 7; ++j)                                                   \
      __builtin_amdgcn_global_load_lds(                                           \
          (const __attribute__((address_space(1))) void*)(gsrc[j] + (u) * BKU),   \
          (__attribute__((address_space(3))) void*)(&S[SLOTB(u) + ldst[j]]), 16, 0, 0); }

  // ---- ds_read offsets (elem); rows 32 elems (64B); swizzle matches staging.
  int q16 = lane & 15;
  int hi = lane >> 4;                // 0..3 -> k-granule
  int kgr = (hi ^ ((q16 >> 1) & 3)) * 8;
  int arow = (wm * 96 + q16) * BKU + kgr;             // + mi*512
  int brow = AELEMS + (wn * 128 + q16) * BKU + kgr;   // + ni*512

  f32x4 acc[6][8] = {};              // [mi][ni] -- 192 regs (AGPR), unspilled at 512 budget
  short8 af[6];
  short8 bf[4];                      // single buffer, two ni-half passes

  // Prologue: stage unit 0.
  STAGE(0);

  #pragma unroll
  for (int u = 0; u < UNITS; ++u) {
    if (u + 1 < UNITS) {
      STAGE(u + 1);                  // 7 loads -> other slot (1-unit DMA lead)
      asm volatile("s_waitcnt vmcnt(7)" ::: "memory");   // unit u's 7 landed
    } else {
      asm volatile("s_waitcnt vmcnt(0)" ::: "memory");
    }
    __builtin_amdgcn_s_barrier();    // all waves: slot u ready; slot u-1 consumed
    __builtin_amdgcn_sched_barrier(0);

    const unsigned short* sb = &S[SLOTB(u)];
    #pragma unroll
    for (int mi = 0; mi < 6; ++mi)
      af[mi] = *(const short8*)&sb[arow + mi * 512];
    #pragma unroll
    for (int ni = 0; ni < 4; ++ni)
      bf[ni] = *(const short8*)&sb[brow + ni * 512];
    asm volatile("s_waitcnt lgkmcnt(0)" ::: "memory");
    __builtin_amdgcn_sched_barrier(0);
    __builtin_amdgcn_s_setprio(1);
    #pragma unroll
    for (int ni = 0; ni < 4; ++ni)
      #pragma unroll
      for (int mi = 0; mi < 6; ++mi)
        acc[mi][ni] = __builtin_amdgcn_mfma_f32_16x16x32_bf16(af[mi], bf[ni], acc[mi][ni], 0, 0, 0);
    __builtin_amdgcn_s_setprio(0);
    #pragma unroll
    for (int ni = 0; ni < 4; ++ni)
      bf[ni] = *(const short8*)&sb[brow + (4 + ni) * 512];
    asm volatile("s_waitcnt lgkmcnt(0)" ::: "memory");
    __builtin_amdgcn_sched_barrier(0);
    __builtin_amdgcn_s_setprio(1);
    #pragma unroll
    for (int ni = 0; ni < 4; ++ni)
      #pragma unroll
      for (int mi = 0; mi < 6; ++mi)
        acc[mi][4 + ni] = __builtin_amdgcn_mfma_f32_16x16x32_bf16(af[mi], bf[ni], acc[mi][4 + ni], 0, 0, 0);
    __builtin_amdgcn_s_setprio(0);
    __builtin_amdgcn_sched_barrier(0);
    // all ds_reads of slot u are consumed before this wave's next barrier -> ring-2 safe
  }

  // ---- Epilogue: y[b,n] = sum_w wnT[w][n] * P[(b,w),n] + bias[n]
  // wave rows: wm*96 + mi*16 + hi*4 + r; batch = by*4 + wm*2 + (mi>=3); w = (mi%3)*16+hi*4+r.
  int b0 = by * 4 + wm * 2;
  #pragma unroll
  for (int ni = 0; ni < 8; ++ni) {
    int ng = n0 + wn * 128 + ni * 16 + q16;
    float s0 = 0.f, s1 = 0.f;
    #pragma unroll
    for (int mi = 0; mi < 3; ++mi) {
      int wbase = mi * 16 + hi * 4;
      f32x4 va = acc[mi][ni];
      f32x4 vb = acc[mi + 3][ni];
      #pragma unroll
      for (int r = 0; r < 4; ++r) {
        float t = wnT[(wbase + r) * NPAD + ng];
        s0 += t * va[r];
        s1 += t * vb[r];
      }
    }
    s0 += __shfl_xor(s0, 16); s0 += __shfl_xor(s0, 32);
    s1 += __shfl_xor(s1, 16); s1 += __shfl_xor(s1, 32);
    if (hi == 0 && ng < OUTD) {
      float bv = bias[ng];
      out[(size_t)b0 * OUTD + ng] = s0 + bv;
      out[(size_t)(b0 + 1) * OUTD + ng] = s1 + bv;
    }
  }
#undef STAGE
#undef SLOTB
}

extern "C" void kernel_launch(void* const* d_in, const int* in_sizes, int n_in,
                              void* d_out, int out_size, void* d_ws, size_t ws_size,
                              hipStream_t stream) {
  const float* x      = (const float*)d_in[0];
  const float* width  = (const float*)d_in[1];
  const float* height = (const float*)d_in[2];
  const float* feat   = (const float*)d_in[3];
  const float* bias   = (const float*)d_in[4];
  float* out = (float*)d_out;

  char* ws = (char*)d_ws;
  unsigned short* A  = (unsigned short*)ws;                        // 6144*768*2 = 9,437,184
  unsigned short* Qt = (unsigned short*)(ws + 9437184);            // 4096*768*2 = 6,291,456
  float* wnT         = (float*)(ws + 9437184 + 6291456);           // 48*4096*4  =   786,432

  prep_all<<<dim3(XPB + NPAD / 4), dim3(256), 0, stream>>>(x, width, height, feat, A, Qt, wnT);
  gemm_main<<<dim3(512), dim3(THREADS), 0, stream>>>(A, Qt, wnT, bias, out);
}

// Round 23
// 48.813 us; speedup vs baseline: 1.1990x; 1.1990x over previous
//
#include <hip/hip_runtime.h>
#include <stdint.h>

#define OUTD 4000
#define NPAD 4096
#define CC 16
#define WW 48
#define HH 48
#define BB 128
#define KD 768          // C*H contraction depth
#define MD 6144         // B*W rows
#define EPSF 1e-6f

#define BM 192          // 4 batches * 48 w
#define BNB 256         // N cols per block
#define BKU 64          // K elems per unit
#define UNITS 12        // 768/64
#define AELEMS (BM * BKU)              // 12288 elems = 24 KB per A slot
#define BELEMS (BNB * BKU)             // 16384 elems = 32 KB per B slot
#define SLOTE (AELEMS + BELEMS)        // 28672 elems = 56 KB per slot
#define THREADS 512
#define XPB 1152        // blocks for x-conversion (16 elems/thread)

using short8  = __attribute__((ext_vector_type(8))) short;
using short16 = __attribute__((ext_vector_type(16))) short;
using f32x4   = __attribute__((ext_vector_type(4))) float;

static __device__ __forceinline__ unsigned short f2bf(float f) {
  union { float f; unsigned int u; } v; v.f = f;
  unsigned int u = v.u;
  unsigned int r = (u + 0x7FFFu + ((u >> 16) & 1u)) >> 16;
  return (unsigned short)r;
}

// ---------------- Fused prep: blocks [0,XPB) convert x -> A (bf16, merged (c,h) K axis,
// 16 elems/thread); blocks [XPB, XPB+1024) normalize weights -> Qt (bf16) + wnT (f32).
__global__ __launch_bounds__(256)
void prep_all(const float* __restrict__ x,
              const float* __restrict__ width,
              const float* __restrict__ height,
              const float* __restrict__ feat,
              unsigned short* __restrict__ A,
              unsigned short* __restrict__ Qt,
              float* __restrict__ wnT) {
  __shared__ float smw[4][WW];
  int bid = blockIdx.x;
  if (bid < XPB) {
    int t = bid * 256 + threadIdx.x;      // XPB*256*16 == BB*CC*WW*HH exactly
    int e = t * 16;
    int h0 = e % HH;                      // 16 | 48: the 16 elems share (b,c,w)
    int w = (e / HH) % WW;
    int c = (e / (HH * WW)) % CC;
    int b = e / (HH * WW * CC);
    float4 v0 = *(const float4*)(x + e);
    float4 v1 = *(const float4*)(x + e + 4);
    float4 v2 = *(const float4*)(x + e + 8);
    float4 v3 = *(const float4*)(x + e + 12);
    short16 o;
    o[0]  = (short)f2bf(v0.x); o[1]  = (short)f2bf(v0.y);
    o[2]  = (short)f2bf(v0.z); o[3]  = (short)f2bf(v0.w);
    o[4]  = (short)f2bf(v1.x); o[5]  = (short)f2bf(v1.y);
    o[6]  = (short)f2bf(v1.z); o[7]  = (short)f2bf(v1.w);
    o[8]  = (short)f2bf(v2.x); o[9]  = (short)f2bf(v2.y);
    o[10] = (short)f2bf(v2.z); o[11] = (short)f2bf(v2.w);
    o[12] = (short)f2bf(v3.x); o[13] = (short)f2bf(v3.y);
    o[14] = (short)f2bf(v3.z); o[15] = (short)f2bf(v3.w);
    *(short16*)&A[(size_t)(b * WW + w) * KD + c * HH + h0] = o;
  } else {
    int lane = threadIdx.x & 63;
    int wv = threadIdx.x >> 6;            // wave 0..3
    int nbase = (bid - XPB) * 4;
    int n = nbase + wv;                   // 0..4095
    bool valid = (n < OUTD);
    float hv = (valid && lane < HH) ? height[n * HH + lane] : 0.f;
    float wvv = (valid && lane < WW) ? width[n * WW + lane] : 0.f;
    float hs = hv * hv, wsum = wvv * wvv;
    #pragma unroll
    for (int off = 32; off > 0; off >>= 1) {
      hs += __shfl_xor(hs, off);
      wsum += __shfl_xor(wsum, off);
    }
    float hnorm = rsqrtf(hs + EPSF);
    float wnorm = rsqrtf(wsum + EPSF);
    if (lane < WW) smw[wv][lane] = wvv * wnorm;   // 0 for invalid n
    if (valid) {
      #pragma unroll
      for (int i = lane; i < KD; i += 64) {
        int c = i / HH, h = i % HH;
        Qt[(size_t)n * KD + i] = f2bf(feat[n * CC + c] * height[n * HH + h] * hnorm);
      }
    } else {
      #pragma unroll
      for (int i = lane; i < KD; i += 64) Qt[(size_t)n * KD + i] = 0;
    }
    __syncthreads();
    if (threadIdx.x < WW) {
      int w = threadIdx.x;
      float4 o = make_float4(smw[0][w], smw[1][w], smw[2][w], smw[3][w]);
      *(float4*)&wnT[w * NPAD + nbase] = o;
    }
  }
}

// ---------------- Main GEMM: P = A (6144x768) * Qt^T (768x4096), fused w-reduction epilogue.
// Best-measured structure (rounds 12/19, replicated r21): 192x256 block, 8 waves (2m x 4n),
// wave tile 96x64 (acc 96 regs -- the proven no-spill profile at the 256-reg/wave budget
// that 2-waves/SIMD residency imposes). 2-slot ring (112 KB LDS), one barrier/unit,
// counted vmcnt(7) with 1-unit DMA lead; all 20 ds_reads issued up front, lgkmcnt(10)
// gates MFMA-A (k-half-1 reads complete under it), lgkmcnt(0) gates MFMA-B.
// ~950 TF effective. Session conclusion: plain-HIP plateau for this shape --
// 1-wave/SIMD unspilled big-acc (r22: 48.6us), 3-blocks/CU small-tile (r14: 62us),
// LDS-free (r13: 121us), coop fusion (r20: 189us) all measured worse.
__global__ __launch_bounds__(THREADS, 2)
void gemm_main(const unsigned short* __restrict__ A,   // [6144][768] bf16 bits
               const unsigned short* __restrict__ Qt,  // [4096][768] bf16 bits
               const float* __restrict__ wnT,          // [48][4096]
               const float* __restrict__ bias,         // [4000]
               float* __restrict__ out) {              // [128][4000]
  __shared__ unsigned short S[2 * SLOTE];   // 114688 B

  int tid = threadIdx.x;
  int lane = tid & 63;
  int wid = tid >> 6;          // 0..7
  int wm = wid >> 2;           // 0..1 -> 96-row slice
  int wn = wid & 3;            // 0..3 -> 64-col subtile

  // 512 blocks: XCD k (= bid&7) owns by in [4k, 4k+4) (A-share 1.15MB, L2-resident),
  // sweeps 16 bx-groups.
  int bid = blockIdx.x;        // 0..511
  int xcd = bid & 7;
  int i = bid >> 3;            // 0..63
  int by = xcd * 4 + (i & 3);  // 0..31
  int bxg = i >> 2;            // 0..15
  int n0 = bxg * BNB;
  int m0 = by * BM;

  // ---- staging: A 3 chunks + B 4 chunks per wave per unit (chunk: 8 rows x 64 elems = 1KB).
  // LDS dest linear; global source granule XOR-pre-swizzled (granule 16B, row 128B):
  // LDS[row][g*8..] holds global[row][(g ^ (row&7))*8..].
  int rsub = lane >> 3;              // 0..7
  int cg = lane & 7;
  int gsw = (cg ^ rsub) * 8;
  const unsigned short* gA[3];
  const unsigned short* gB[4];
  #pragma unroll
  for (int j = 0; j < 3; ++j)
    gA[j] = A + (size_t)(m0 + (wid * 3 + j) * 8 + rsub) * KD + gsw;
  #pragma unroll
  for (int j = 0; j < 4; ++j)
    gB[j] = Qt + (size_t)(n0 + (wid * 4 + j) * 8 + rsub) * KD + gsw;
  int aD[3], bD[4];
  #pragma unroll
  for (int j = 0; j < 3; ++j) aD[j] = (wid * 3 + j) * 512;
  #pragma unroll
  for (int j = 0; j < 4; ++j) bD[j] = AELEMS + (wid * 4 + j) * 512;

#define SLOTB(u) (((u) & 1) * SLOTE)
#define STAGE(u)                                                                    \
  { _Pragma("unroll")                                                               \
    for (int j = 0; j < 3; ++j)                                                     \
      __builtin_amdgcn_global_load_lds(                                             \
          (const __attribute__((address_space(1))) void*)(gA[j] + (u) * BKU),       \
          (__attribute__((address_space(3))) void*)(&S[SLOTB(u) + aD[j]]), 16, 0, 0); \
    _Pragma("unroll")                                                               \
    for (int j = 0; j < 4; ++j)                                                     \
      __builtin_amdgcn_global_load_lds(                                             \
          (const __attribute__((address_space(1))) void*)(gB[j] + (u) * BKU),       \
          (__attribute__((address_space(3))) void*)(&S[SLOTB(u) + bD[j]]), 16, 0, 0); }

  // ---- ds_read offsets (elem); rows 64 elems (128B); swizzle matches staging.
  int q16 = lane & 15;
  int hi = lane >> 4;                // 0..3
  int q7 = q16 & 7;
  int kg0 = ((0 * 4 + hi) ^ q7) * 8;
  int kg1 = ((1 * 4 + hi) ^ q7) * 8;
  int arow = (wm * 96 + q16) * BKU;              // + mi*16*64 + kg + SLOTB
  int brow = AELEMS + (wn * 64 + q16) * BKU;     // + ni*16*64 + kg + SLOTB

  f32x4 acc[6][4] = {};
  short8 afA[6], bfA[4], afB[6], bfB[4];

#define DSREAD_H(afX, bfX, u, kg)                                      \
  { const unsigned short* sb = &S[SLOTB(u)];                           \
    _Pragma("unroll")                                                  \
    for (int mi = 0; mi < 6; ++mi)                                     \
      afX[mi] = *(const short8*)&sb[arow + mi * 16 * BKU + (kg)];      \
    _Pragma("unroll")                                                  \
    for (int ni = 0; ni < 4; ++ni)                                     \
      bfX[ni] = *(const short8*)&sb[brow + ni * 16 * BKU + (kg)]; }

#define MFMA24(afX, bfX)                                               \
  { _Pragma("unroll")                                                  \
    for (int ni = 0; ni < 4; ++ni)                                     \
      _Pragma("unroll")                                                \
      for (int mi = 0; mi < 6; ++mi)                                   \
        acc[mi][ni] = __builtin_amdgcn_mfma_f32_16x16x32_bf16(afX[mi], bfX[ni], acc[mi][ni], 0, 0, 0); }

  // Prologue: stage unit 0.
  STAGE(0);

  #pragma unroll
  for (int u = 0; u < UNITS; ++u) {
    if (u + 1 < UNITS) {
      STAGE(u + 1);                            // 7 loads -> other slot (1-unit DMA lead)
      asm volatile("s_waitcnt vmcnt(7)" ::: "memory");   // unit u's 7 landed; u+1's stay in flight
    } else {
      asm volatile("s_waitcnt vmcnt(0)" ::: "memory");
    }
    __builtin_amdgcn_s_barrier();              // all waves: slot u ready
    __builtin_amdgcn_sched_barrier(0);

    DSREAD_H(afA, bfA, u, kg0);                // k-half 0 reads (10)
    DSREAD_H(afB, bfB, u, kg1);                // k-half 1 reads (10) -- issued immediately
    asm volatile("s_waitcnt lgkmcnt(10)" ::: "memory");  // k-half 0 landed; k-half 1 in flight
    __builtin_amdgcn_sched_barrier(0);
    __builtin_amdgcn_s_setprio(1);
    MFMA24(afA, bfA);                          // k-half-1 reads complete under this cluster
    __builtin_amdgcn_s_setprio(0);
    asm volatile("s_waitcnt lgkmcnt(0)" ::: "memory");
    __builtin_amdgcn_sched_barrier(0);
    __builtin_amdgcn_s_setprio(1);
    MFMA24(afB, bfB);
    __builtin_amdgcn_s_setprio(0);
    __builtin_amdgcn_sched_barrier(0);
    // each wave's slot-u reads are lgkm-drained before its MFMA cluster ends, which
    // precedes barrier(u+1), which precedes STAGE(u+2) overwriting slot u.
  }

  // ---- Epilogue: y[b,n] = sum_w wnT[w][n] * P[(b,w),n] + bias[n]
  // wave rows: wm*96 + mi*16 + hi*4 + rr; batch = by*4 + wm*2 + (mi>=3); w = (mi%3)*16+hi*4+rr.
  int b0 = by * 4 + wm * 2;
  #pragma unroll
  for (int ni = 0; ni < 4; ++ni) {
    int ng = n0 + wn * 64 + ni * 16 + q16;
    float s0 = 0.f, s1 = 0.f;
    #pragma unroll
    for (int mi = 0; mi < 3; ++mi) {
      int wbase = mi * 16 + hi * 4;
      f32x4 va = acc[mi][ni];
      f32x4 vb = acc[mi + 3][ni];
      #pragma unroll
      for (int r = 0; r < 4; ++r) {
        float t = wnT[(wbase + r) * NPAD + ng];
        s0 += t * va[r];
        s1 += t * vb[r];
      }
    }
    s0 += __shfl_xor(s0, 16); s0 += __shfl_xor(s0, 32);
    s1 += __shfl_xor(s1, 16); s1 += __shfl_xor(s1, 32);
    if (hi == 0 && ng < OUTD) {
      float bv = bias[ng];
      out[(size_t)b0 * OUTD + ng] = s0 + bv;
      out[(size_t)(b0 + 1) * OUTD + ng] = s1 + bv;
    }
  }
#undef STAGE
#undef SLOTB
#undef DSREAD_H
#undef MFMA24
}

extern "C" void kernel_launch(void* const* d_in, const int* in_sizes, int n_in,
                              void* d_out, int out_size, void* d_ws, size_t ws_size,
                              hipStream_t stream) {
  const float* x      = (const float*)d_in[0];
  const float* width  = (const float*)d_in[1];
  const float* height = (const float*)d_in[2];
  const float* feat   = (const float*)d_in[3];
  const float* bias   = (const float*)d_in[4];
  float* out = (float*)d_out;

  char* ws = (char*)d_ws;
  unsigned short* A  = (unsigned short*)ws;                        // 6144*768*2 = 9,437,184
  unsigned short* Qt = (unsigned short*)(ws + 9437184);            // 4096*768*2 = 6,291,456
  float* wnT         = (float*)(ws + 9437184 + 6291456);           // 48*4096*4  =   786,432

  prep_all<<<dim3(XPB + NPAD / 4), dim3(256), 0, stream>>>(x, width, height, feat, A, Qt, wnT);
  gemm_main<<<dim3(512), dim3(THREADS), 0, stream>>>(A, Qt, wnT, bias, out);
}